// Round 1
// 2070.962 us; speedup vs baseline: 1.2886x; 1.2886x over previous
//
#include <hip/hip_runtime.h>

typedef __attribute__((ext_vector_type(8))) short short8;
typedef __attribute__((ext_vector_type(4))) float f32x4;

#define LNE 1e-5f

__device__ __forceinline__ unsigned short f2bf(float f) {
  union { float f; unsigned int u; } v; v.f = f;
  unsigned int r = v.u + 0x7fffu + ((v.u >> 16) & 1u);
  return (unsigned short)(r >> 16);
}
__device__ __forceinline__ float bf2f(unsigned short s) {
  union { unsigned int u; float f; } v; v.u = ((unsigned int)s) << 16;
  return v.f;
}
__device__ __forceinline__ unsigned int pk2(float a, float b) {
  return (unsigned int)f2bf(a) | ((unsigned int)f2bf(b) << 16);
}

// ---- weight prep: fp32 -> bf16, transposed to [n][k] ----
// ws layout (ushort elems):
//   wqkvT [1152][384]  rows: mat*384 + head*48 + e       (0 .. 442368)
//   woT   [384][384]   woT[n][d] = wo[d][n]              (442368 .. 589824)
//   w1T   [1536][384]  w1T[n][d] = w1[d][n]              (589824 .. 1179648)
//   w2T   [384][1536]  w2T[n][c] = w2[c][n]              (1179648 .. 1769472)
__global__ void prep_kernel(const float* __restrict__ wq, const float* __restrict__ wk,
                            const float* __restrict__ wv, const float* __restrict__ wo,
                            const float* __restrict__ w1, const float* __restrict__ w2,
                            unsigned short* __restrict__ ws) {
  int idx = blockIdx.x * 256 + threadIdx.x;
  if (idx < 442368) {
    int n = idx / 384, d = idx % 384;
    int mat = n / 384, rem = n % 384, head = rem / 48, e = rem % 48;
    const float* w = (mat == 0) ? wq : ((mat == 1) ? wk : wv);
    ws[idx] = f2bf(w[(head * 384 + d) * 48 + e]);
  } else if (idx < 589824) {
    int j = idx - 442368; int n = j / 384, d = j % 384;
    ws[idx] = f2bf(wo[d * 384 + n]);
  } else if (idx < 1179648) {
    int j = idx - 589824; int n = j / 384, d = j % 384;
    ws[idx] = f2bf(w1[d * 1536 + n]);
  } else if (idx < 1769472) {
    int j = idx - 1179648; int n = j / 1536, c = j % 1536;
    ws[idx] = f2bf(w2[c * 384 + n]);
  }
}

// ---- fused transformer block: one workgroup (512 thr / 8 waves) per batch ----
// 8 waves = 2 waves/SIMD (LDS 147.5KB -> 1 block/CU). Attention runs 2 heads
// concurrently (waves 0-3 = head h, waves 4-7 = head h+1, double-buffered
// sQ/sK/sVT). Phases 2/3 split tiles across all 8 waves.
__global__ __launch_bounds__(512, 2) void block_fused(
    const float* __restrict__ x,
    const float* __restrict__ bq, const float* __restrict__ bk, const float* __restrict__ bv,
    const float* __restrict__ bo, const float* __restrict__ b1, const float* __restrict__ b2,
    const float* __restrict__ g1, const float* __restrict__ be1,
    const float* __restrict__ g2, const float* __restrict__ be2,
    const unsigned short* __restrict__ wt,
    float* __restrict__ out) {
  // strides: 392 = 384+8 (row stride ≡ 4 mod 32 dwords -> 2-way bank alias only, 16B aligned)
  //          72  = 64+8  (same property)
  __shared__ __align__(16) unsigned short sH[64 * 392];      // h after LN1; h2 after LN2
  __shared__ __align__(16) unsigned short sA[64 * 392];      // attn concat; reused as U (FFN1 chunk)
  __shared__ __align__(16) unsigned short sQ[2][64 * 72];    // q per head-set; reused as P; aliased as LN2 scratch
  __shared__ __align__(16) unsigned short sK[2][64 * 72];    // k per head-set
  __shared__ __align__(16) unsigned short sVT[2][48 * 72];   // v^T [e][s] per head-set

  const int tid  = threadIdx.x;
  const int wave = tid >> 6, lane = tid & 63;
  const int quad = lane >> 4, l15 = lane & 15;
  const int g = wave >> 2, w4 = wave & 3;   // head-set, wave-within-set
  const int b = blockIdx.x;

  const unsigned short* wqkvT = wt;
  const unsigned short* woT   = wt + 442368;
  const unsigned short* w1T   = wt + 589824;
  const unsigned short* w2T   = wt + 1179648;

  // ================= Phase 0: LN1, x -> sH (bf16) =================
  {
    const int r = tid >> 3, sub = tid & 7;    // 8 threads per row
    const float* xr = x + ((size_t)b * 64 + r) * 384 + sub * 48;
    float s = 0.f, s2 = 0.f;
#pragma unroll
    for (int i = 0; i < 12; ++i) {
      float4 v = ((const float4*)xr)[i];
      s  += v.x + v.y + v.z + v.w;
      s2 += v.x * v.x + v.y * v.y + v.z * v.z + v.w * v.w;
    }
    s  += __shfl_xor(s, 1);  s  += __shfl_xor(s, 2);  s  += __shfl_xor(s, 4);
    s2 += __shfl_xor(s2, 1); s2 += __shfl_xor(s2, 2); s2 += __shfl_xor(s2, 4);
    float mu = s * (1.f / 384.f);
    float rstd = rsqrtf(s2 * (1.f / 384.f) - mu * mu + LNE);
#pragma unroll
    for (int i = 0; i < 12; ++i) {
      float4 v = ((const float4*)xr)[i];
      int c = sub * 48 + i * 4;
      float h0 = (v.x - mu) * rstd * g1[c + 0] + be1[c + 0];
      float h1 = (v.y - mu) * rstd * g1[c + 1] + be1[c + 1];
      float h2 = (v.z - mu) * rstd * g1[c + 2] + be1[c + 2];
      float h3 = (v.w - mu) * rstd * g1[c + 3] + be1[c + 3];
      *(uint2*)&sH[r * 392 + c] = make_uint2(pk2(h0, h1), pk2(h2, h3));
    }
  }
  __syncthreads();

  // ================= Phase 1: attention, 2 heads per iteration =================
#pragma unroll 1
  for (int hp = 0; hp < 4; ++hp) {
    const int h = hp * 2 + g;
    {   // zero-pad q/k cols 48..63 of own set (K=64 MFMA padding; P overwrote last iter)
      int set = tid >> 8, t2 = tid & 255;
      int rr = t2 >> 2, cc = 48 + (t2 & 3) * 4;
      *(uint2*)&sQ[set][rr * 72 + cc] = make_uint2(0, 0);
      *(uint2*)&sK[set][rr * 72 + cc] = make_uint2(0, 0);
    }
    // --- QKV projections for this set's head: 36 tiles across 4 waves, 3 chains in flight ---
#pragma unroll 3
    for (int it = 0; it < 9; ++it) {
      int tile = w4 + 4 * it;               // 0..35
      int mat = tile / 12, sub = tile % 12;
      int mt = sub / 3, et = sub % 3;
      const unsigned short* bp = wqkvT + (size_t)((mat * 8 + h) * 48 + et * 16 + l15) * 384 + quad * 8;
      const unsigned short* ap = sH + (mt * 16 + l15) * 392 + quad * 8;
      f32x4 acc = {0.f, 0.f, 0.f, 0.f};
#pragma unroll
      for (int k = 0; k < 12; ++k) {
        short8 a  = *(const short8*)(ap + k * 32);
        short8 bb = *(const short8*)(bp + k * 32);
        acc = __builtin_amdgcn_mfma_f32_16x16x32_bf16(a, bb, acc, 0, 0, 0);
      }
      const float* bias = (mat == 0) ? bq : ((mat == 1) ? bk : bv);
      float bsv = bias[h * 48 + et * 16 + l15];
      if (mat == 2) {   // v -> sVT[e][s], contiguous in s -> b64 pack
        *(uint2*)&sVT[g][(et * 16 + l15) * 72 + mt * 16 + quad * 4] =
            make_uint2(pk2(acc[0] + bsv, acc[1] + bsv), pk2(acc[2] + bsv, acc[3] + bsv));
      } else {          // q/k -> [t][e], scalar scatter
        unsigned short* dst = (mat == 0) ? &sQ[g][0] : &sK[g][0];
#pragma unroll
        for (int i = 0; i < 4; ++i)
          dst[(mt * 16 + quad * 4 + i) * 72 + et * 16 + l15] = f2bf(acc[i] + bsv);
      }
    }
    __syncthreads();

    // --- S = q k^T (wave owns rows 16*w4..+15), causal softmax in-register ---
    f32x4 sc[4];
#pragma unroll
    for (int ts = 0; ts < 4; ++ts) {
      f32x4 acc = {0.f, 0.f, 0.f, 0.f};
#pragma unroll
      for (int k = 0; k < 2; ++k) {
        short8 a  = *(const short8*)&sQ[g][(w4 * 16 + l15) * 72 + k * 32 + quad * 8];
        short8 bb = *(const short8*)&sK[g][(ts * 16 + l15) * 72 + k * 32 + quad * 8];
        acc = __builtin_amdgcn_mfma_f32_16x16x32_bf16(a, bb, acc, 0, 0, 0);
      }
      sc[ts] = acc;
    }
    const float scale = 0.14433756729740645f;  // 48^-0.5
#pragma unroll
    for (int i = 0; i < 4; ++i) {
      int t = w4 * 16 + quad * 4 + i;
      float vv[4];
#pragma unroll
      for (int ts = 0; ts < 4; ++ts) {
        int s_ = ts * 16 + l15;
        float v = sc[ts][i] * scale;
        vv[ts] = (s_ <= t) ? v : -INFINITY;
      }
      float mx = fmaxf(fmaxf(vv[0], vv[1]), fmaxf(vv[2], vv[3]));
      mx = fmaxf(mx, __shfl_xor(mx, 1)); mx = fmaxf(mx, __shfl_xor(mx, 2));
      mx = fmaxf(mx, __shfl_xor(mx, 4)); mx = fmaxf(mx, __shfl_xor(mx, 8));
      float sum = 0.f;
#pragma unroll
      for (int ts = 0; ts < 4; ++ts) { vv[ts] = __expf(vv[ts] - mx); sum += vv[ts]; }
      sum += __shfl_xor(sum, 1); sum += __shfl_xor(sum, 2);
      sum += __shfl_xor(sum, 4); sum += __shfl_xor(sum, 8);
      float inv = 1.f / sum;
#pragma unroll
      for (int ts = 0; ts < 4; ++ts)           // P -> sQ[t][s] (q is dead; own rows only)
        sQ[g][t * 72 + ts * 16 + l15] = f2bf(vv[ts] * inv);
    }
    // --- attn^T = V^T P^T ; write attn[t][h*48+e] (b64 pack) ---
#pragma unroll
    for (int et = 0; et < 3; ++et) {
      f32x4 acc = {0.f, 0.f, 0.f, 0.f};
#pragma unroll
      for (int k = 0; k < 2; ++k) {
        short8 a  = *(const short8*)&sVT[g][(et * 16 + l15) * 72 + k * 32 + quad * 8];
        short8 bb = *(const short8*)&sQ[g][(w4 * 16 + l15) * 72 + k * 32 + quad * 8];
        acc = __builtin_amdgcn_mfma_f32_16x16x32_bf16(a, bb, acc, 0, 0, 0);
      }
      *(uint2*)&sA[(w4 * 16 + l15) * 392 + h * 48 + et * 16 + quad * 4] =
          make_uint2(pk2(acc[0], acc[1]), pk2(acc[2], acc[3]));
    }
    __syncthreads();
  }

  // ================= Phase 2: out-proj + residual + LN2 =================
  {
    const int mt2 = wave >> 1, nh = wave & 1;  // row-tile, n-half
    float* sRed = (float*)&sQ[0][0];           // sQ dead -> LN2 cross-wave scratch
    f32x4 oacc[12];
#pragma unroll
    for (int nl = 0; nl < 12; ++nl) oacc[nl] = (f32x4){0.f, 0.f, 0.f, 0.f};
#pragma unroll 2
    for (int k = 0; k < 12; ++k) {
      short8 a = *(const short8*)&sA[(mt2 * 16 + l15) * 392 + k * 32 + quad * 8];
#pragma unroll
      for (int nl = 0; nl < 12; ++nl) {
        int nt = nh * 12 + nl;
        short8 bb = *(const short8*)(woT + (size_t)(nt * 16 + l15) * 384 + k * 32 + quad * 8);
        oacc[nl] = __builtin_amdgcn_mfma_f32_16x16x32_bf16(a, bb, oacc[nl], 0, 0, 0);
      }
    }
#pragma unroll
    for (int nl = 0; nl < 12; ++nl) {
      int nt = nh * 12 + nl;
      float bov = bo[nt * 16 + l15];
#pragma unroll
      for (int i = 0; i < 4; ++i) {
        float hv = bf2f(sH[(mt2 * 16 + quad * 4 + i) * 392 + nt * 16 + l15]);
        oacc[nl][i] += bov + hv;    // r = h + attn@wo + bo
      }
    }
    // per-wave partial row stats (192 of 384 cols) -> LDS -> combine with partner
    float sown[4], s2own[4];
#pragma unroll
    for (int i = 0; i < 4; ++i) {
      float s = 0.f, s2 = 0.f;
#pragma unroll
      for (int nl = 0; nl < 12; ++nl) { float v = oacc[nl][i]; s += v; s2 += v * v; }
      s  += __shfl_xor(s, 1);  s  += __shfl_xor(s, 2);  s  += __shfl_xor(s, 4);  s  += __shfl_xor(s, 8);
      s2 += __shfl_xor(s2, 1); s2 += __shfl_xor(s2, 2); s2 += __shfl_xor(s2, 4); s2 += __shfl_xor(s2, 8);
      sown[i] = s; s2own[i] = s2;
      if (l15 == 0) {
        int row = mt2 * 16 + quad * 4 + i;
        sRed[(nh * 64 + row) * 2 + 0] = s;
        sRed[(nh * 64 + row) * 2 + 1] = s2;
      }
    }
    __syncthreads();
    float mu_[4], rstd_[4];
#pragma unroll
    for (int i = 0; i < 4; ++i) {
      int row = mt2 * 16 + quad * 4 + i;
      float st  = sown[i]  + sRed[((nh ^ 1) * 64 + row) * 2 + 0];
      float s2t = s2own[i] + sRed[((nh ^ 1) * 64 + row) * 2 + 1];
      float mu = st * (1.f / 384.f);
      mu_[i] = mu;
      rstd_[i] = rsqrtf(s2t * (1.f / 384.f) - mu * mu + LNE);
    }
#pragma unroll
    for (int nl = 0; nl < 12; ++nl) {
      int n = (nh * 12 + nl) * 16 + l15;
      float gv = g2[n], bev = be2[n];
#pragma unroll
      for (int i = 0; i < 4; ++i) {
        float h2v = (oacc[nl][i] - mu_[i]) * rstd_[i] * gv + bev;
        sH[(mt2 * 16 + quad * 4 + i) * 392 + n] = f2bf(h2v);   // h2 overwrites h (own region)
      }
    }
  }
  __syncthreads();

  // ================= Phase 3: FFN (chunks of 384 over 1536) =================
  f32x4 facc[4][3];
#pragma unroll
  for (int mt = 0; mt < 4; ++mt)
#pragma unroll
    for (int nl = 0; nl < 3; ++nl) facc[mt][nl] = (f32x4){0.f, 0.f, 0.f, 0.f};

#pragma unroll 1
  for (int c = 0; c < 4; ++c) {
    // FFN1: U^T = w1_chunk^T @ h2^T -> write U[t][cl] (b64 pack), relu+bias fused
#pragma unroll 1
    for (int ml = 0; ml < 3; ++ml) {
      int mt = wave * 3 + ml;     // chunk-local col-tile 0..23
      const unsigned short* ap = w1T + (size_t)(c * 384 + mt * 16 + l15) * 384 + quad * 8;
#pragma unroll 2
      for (int nt = 0; nt < 4; ++nt) {
        f32x4 acc = {0.f, 0.f, 0.f, 0.f};
#pragma unroll
        for (int k = 0; k < 12; ++k) {
          short8 a  = *(const short8*)(ap + k * 32);
          short8 bb = *(const short8*)&sH[(nt * 16 + l15) * 392 + k * 32 + quad * 8];
          acc = __builtin_amdgcn_mfma_f32_16x16x32_bf16(a, bb, acc, 0, 0, 0);
        }
        int rbase = c * 384 + mt * 16 + quad * 4;
        float u0 = fmaxf(acc[0] + b1[rbase + 0], 0.f);
        float u1 = fmaxf(acc[1] + b1[rbase + 1], 0.f);
        float u2 = fmaxf(acc[2] + b1[rbase + 2], 0.f);
        float u3 = fmaxf(acc[3] + b1[rbase + 3], 0.f);
        *(uint2*)&sA[(nt * 16 + l15) * 392 + mt * 16 + quad * 4] =
            make_uint2(pk2(u0, u1), pk2(u2, u3));
      }
    }
    __syncthreads();
    // FFN2: wave owns n-tiles wave*3..+2 (each w2 element read once per block)
#pragma unroll 2
    for (int k = 0; k < 12; ++k) {
      short8 a[4];
#pragma unroll
      for (int mt = 0; mt < 4; ++mt)
        a[mt] = *(const short8*)&sA[(mt * 16 + l15) * 392 + k * 32 + quad * 8];
#pragma unroll
      for (int nl = 0; nl < 3; ++nl) {
        int n = (wave * 3 + nl) * 16 + l15;
        short8 bb = *(const short8*)(w2T + (size_t)n * 1536 + c * 384 + k * 32 + quad * 8);
#pragma unroll
        for (int mt = 0; mt < 4; ++mt)
          facc[mt][nl] = __builtin_amdgcn_mfma_f32_16x16x32_bf16(a[mt], bb, facc[mt][nl], 0, 0, 0);
      }
    }
    __syncthreads();
  }

  // ================= Epilogue: out = h2 + ff + b2 =================
#pragma unroll
  for (int nl = 0; nl < 3; ++nl) {
    int n = (wave * 3 + nl) * 16 + l15;
    float b2v = b2[n];
#pragma unroll
    for (int mt = 0; mt < 4; ++mt) {
#pragma unroll
      for (int i = 0; i < 4; ++i) {
        int t = mt * 16 + quad * 4 + i;
        float v = facc[mt][nl][i] + b2v + bf2f(sH[t * 392 + n]);
        out[((size_t)b * 64 + t) * 384 + n] = v;
      }
    }
  }
}

extern "C" void kernel_launch(void* const* d_in, const int* in_sizes, int n_in,
                              void* d_out, int out_size, void* d_ws, size_t ws_size,
                              hipStream_t stream) {
  const float* x   = (const float*)d_in[0];
  const float* wq  = (const float*)d_in[1];
  const float* bq  = (const float*)d_in[2];
  const float* wk  = (const float*)d_in[3];
  const float* bk  = (const float*)d_in[4];
  const float* wv  = (const float*)d_in[5];
  const float* bv  = (const float*)d_in[6];
  const float* wo  = (const float*)d_in[7];
  const float* bo  = (const float*)d_in[8];
  const float* w1  = (const float*)d_in[9];
  const float* b1  = (const float*)d_in[10];
  const float* w2  = (const float*)d_in[11];
  const float* b2  = (const float*)d_in[12];
  const float* g1  = (const float*)d_in[13];
  const float* be1 = (const float*)d_in[14];
  const float* g2  = (const float*)d_in[15];
  const float* be2 = (const float*)d_in[16];
  unsigned short* wt = (unsigned short*)d_ws;
  float* out = (float*)d_out;

  int nbatch = in_sizes[0] / (64 * 384);    // 2048
  prep_kernel<<<(1769472 + 255) / 256, 256, 0, stream>>>(wq, wk, wv, wo, w1, w2, wt);
  block_fused<<<nbatch, 512, 0, stream>>>(x, bq, bk, bv, bo, b1, b2,
                                          g1, be1, g2, be2, wt, out);
}